// Round 8
// baseline (94.465 us; speedup 1.0000x reference)
//
#include <hip/hip_runtime.h>
#include <math.h>

// Fused fab_penalty_ls_curve: 13-point stencil over eps + global reduction.
// R7 post-mortem: 92 us invariant to grid shape/pipeline depth. Remaining
// suspects common to all configs: (1) every dwordx4 misaligned by 8B (line
// splits on 100% of loads), (2) 3 quarter-rate trans ops/element, (3) 1024
// same-address atomics at tail.
// R8: ownership shifted +2 cols -> all loads 16B-aligned; v_rsq replaces
// sqrt+rcp (3->2 trans/el); block partials scattered to 64 ws slots + tiny
// finisher kernel. Structure otherwise identical to R7 (clean A/B).

typedef float f2 __attribute__((ext_vector_type(2)));
typedef float f4 __attribute__((ext_vector_type(4)));   // 16B-aligned

constexpr float SCF = 1e-12f;
constexpr float EVF = 4.6415888336e-6f;        // 1e-32^(1/6)
constexpr float PID = 2.8559933214452666f;     // pi/1.1
constexpr float PIH = 1.5707963268f;
constexpr int   RS  = 64;                      // rows per strip (mult of 8)

struct Row { f4 lo, hi; };                     // cols 4g..4g+3, 4g+4..4g+7

__device__ __forceinline__ float C(const Row& r, int k) {
    return k < 4 ? r.lo[k] : r.hi[k - 4];      // col 4g+k = j-2+k (j=4g+2)
}
__device__ __forceinline__ void load_row(Row& r, const float* p) {
    r.lo = *(const f4*)p;                      // aligned dwordx4
    r.hi = *(const f4*)(p + 4);                // aligned dwordx4
}
__device__ __forceinline__ f2 mk(float a, float b) { f2 v; v.x = a; v.y = b; return v; }
__device__ __forceinline__ f2 fma2(f2 a, f2 b, f2 c) { return __builtin_elementwise_fma(a, b, c); }
__device__ __forceinline__ f2 max2(f2 a, f2 b) { return __builtin_elementwise_max(a, b); }
__device__ __forceinline__ f2 min2(f2 a, f2 b) { return __builtin_elementwise_min(a, b); }
__device__ __forceinline__ f2 abs2(f2 a) { return __builtin_elementwise_abs(a); }
__device__ __forceinline__ f2 rcp2(f2 a) {
    return mk(__builtin_amdgcn_rcpf(a.x), __builtin_amdgcn_rcpf(a.y));
}
__device__ __forceinline__ f2 rsq2(f2 a) {
    return mk(__builtin_amdgcn_rsqf(a.x), __builtin_amdgcn_rsqf(a.y));
}

// ---- packed math for output rows (i, i+1): R0..R5 = rows i-2 .. i+3 ----
__device__ __forceinline__ f2 compute_pair(const Row& R0, const Row& R1,
                                           const Row& R2, const Row& R3,
                                           const Row& R4, const Row& R5,
                                           f2 inv2d, f2 inv4dd) {
    f2 dif[6];                                 // (rp1-rm1) at cols j-1..j+4
    #pragma unroll
    for (int k = 0; k < 6; ++k)
        dif[k] = mk(C(R3, k + 1) - C(R1, k + 1),
                    C(R4, k + 1) - C(R2, k + 1));
    f2 Pz[8];                                  // center rows, cols j-2..j+5
    #pragma unroll
    for (int k = 0; k < 8; ++k)
        Pz[k] = mk(C(R2, k), C(R3, k));

    const f2 sc2 = mk(SCF, SCF);
    f2 part = mk(0.0f, 0.0f);
    #pragma unroll
    for (int q = 0; q < 4; ++q) {
        const f2 c00 = Pz[q + 2];
        const f2 ex  = fma2(dif[q + 1], inv2d, sc2);
        const f2 ey  = fma2(Pz[q + 3] - Pz[q + 1], inv2d, sc2);
        const f2 sxx = mk(C(R4, q + 2) + C(R0, q + 2),
                          C(R5, q + 2) + C(R1, q + 2));
        const f2 exx = (sxx - 2.0f * c00) * inv4dd;
        const f2 eyy = (Pz[q + 4] + Pz[q] - 2.0f * c00) * inv4dd;
        const f2 exy = (dif[q + 2] - dif[q]) * inv4dd;

        // ev = max(sqrt(s2), EVF); 1/ev^3 = min(rsq^3, EVF^-3) — one rsq,
        // no sqrt, no rcp for the cube.
        const f2 s2  = fma2(ex, ex, ey * ey);
        const f2 rsq = rsq2(s2);
        const f2 ev  = max2(s2 * rsq, mk(EVF, EVF));
        const f2 iv3 = min2(rsq * rsq * rsq, mk(1e16f, 1e16f));
        const f2 num = fma2(ex * ex, eyy,
                       fma2(-2.0f * (ex * ey), exy, (ey * ey) * exx));
        const f2 kabs = abs2(num) * iv3;

        // |atan(ev/w)| = atan(ev/|w|): min/max range reduction, 1 rcp
        const f2 aw = abs2(c00 + 1e-6f);
        const f2 mx = max2(ev, aw);
        const f2 mn = min2(ev, aw);
        const f2 t  = mn * rcp2(mx);
        const f2 t2 = t * t;
        f2 pl = fma2(t2, mk(-0.01172120f, -0.01172120f), mk(0.05265332f, 0.05265332f));
        pl = fma2(t2, pl, mk(-0.11643287f, -0.11643287f));
        pl = fma2(t2, pl, mk(0.19354346f, 0.19354346f));
        pl = fma2(t2, pl, mk(-0.33262347f, -0.33262347f));
        pl = fma2(t2, pl, mk(0.99997726f, 0.99997726f));
        pl = pl * t;
        f2 at;
        at.x = (ev.x > aw.x) ? PIH - pl.x : pl.x;
        at.y = (ev.y > aw.y) ? PIH - pl.y : pl.y;

        // max(NaN,0)=0 implements nansum
        part = part + max2(fma2(kabs, at, mk(-PID, -PID)), mk(0.0f, 0.0f));
    }
    return part;
}

// ---- frame-path helpers: numpy edge_order=1 gradients on global memory ----
__device__ __forceinline__ float eg(const float* __restrict__ e, int n, int i, int j) {
    return e[(size_t)i * (size_t)n + j];
}
__device__ __forceinline__ float gex(const float* __restrict__ e, int n, int i, int j,
                                     float inv_d, float inv_2d) {
    float v;
    if (i == 0)          v = (eg(e, n, 1, j) - eg(e, n, 0, j)) * inv_d;
    else if (i == n - 1) v = (eg(e, n, n - 1, j) - eg(e, n, n - 2, j)) * inv_d;
    else                 v = (eg(e, n, i + 1, j) - eg(e, n, i - 1, j)) * inv_2d;
    return v + SCF;
}
__device__ __forceinline__ float gey(const float* __restrict__ e, int n, int i, int j,
                                     float inv_d, float inv_2d) {
    float v;
    if (j == 0)          v = (eg(e, n, i, 1) - eg(e, n, i, 0)) * inv_d;
    else if (j == n - 1) v = (eg(e, n, i, n - 1) - eg(e, n, i, n - 2)) * inv_d;
    else                 v = (eg(e, n, i, j + 1) - eg(e, n, i, j - 1)) * inv_2d;
    return v + SCF;
}

__global__ __launch_bounds__(256, 4)
void fab_fused(const float* __restrict__ eps, const float* __restrict__ gs,
               float* __restrict__ ws, int n, int G2, int nfr) {
    const float d       = *gs;
    const float inv_2d  = 0.5f / d;
    const float inv_4dd = inv_2d * inv_2d;

    float acc = 0.0f;

    // ========== frame (edge_order=1 one-sided) — 96 elements/block =========
    if (threadIdx.x < 96) {
        const int bflat = blockIdx.y * gridDim.x + blockIdx.x;
        const int idx = bflat * 96 + (int)threadIdx.x;
        if (idx < nfr) {
            const float inv_d = inv_2d + inv_2d;
            int i, j;
            if (idx < 4 * n) {
                const int rr = (idx >= n) + (idx >= 2 * n) + (idx >= 3 * n);
                j = idx - rr * n;
                i = (rr < 2) ? rr : (n - 4) + rr;             // 0,1,n-2,n-1
            } else {
                const int t = idx - 4 * n;
                i = 2 + (t >> 3);                             // rows 2..n-3
                const int cc = t & 7;
                j = (cc < 2) ? cc : (n - 8) + cc;             // 0,1, n-6..n-1
            }

            const float ex0 = gex(eps, n, i, j, inv_d, inv_2d);
            const float ey0 = gey(eps, n, i, j, inv_d, inv_2d);

            float exx, exy, eyy;
            if (i == 0)
                exx = (gex(eps, n, 1, j, inv_d, inv_2d) - ex0) * inv_d;
            else if (i == n - 1)
                exx = (ex0 - gex(eps, n, n - 2, j, inv_d, inv_2d)) * inv_d;
            else
                exx = (gex(eps, n, i + 1, j, inv_d, inv_2d)
                     - gex(eps, n, i - 1, j, inv_d, inv_2d)) * inv_2d;

            if (j == 0)
                exy = (gex(eps, n, i, 1, inv_d, inv_2d) - ex0) * inv_d;
            else if (j == n - 1)
                exy = (ex0 - gex(eps, n, i, n - 2, inv_d, inv_2d)) * inv_d;
            else
                exy = (gex(eps, n, i, j + 1, inv_d, inv_2d)
                     - gex(eps, n, i, j - 1, inv_d, inv_2d)) * inv_2d;

            if (j == 0)
                eyy = (gey(eps, n, i, 1, inv_d, inv_2d) - ey0) * inv_d;
            else if (j == n - 1)
                eyy = (ey0 - gey(eps, n, i, n - 2, inv_d, inv_2d)) * inv_d;
            else
                eyy = (gey(eps, n, i, j + 1, inv_d, inv_2d)
                     - gey(eps, n, i, j - 1, inv_d, inv_2d)) * inv_2d;

            const float ev = fmaxf(__builtin_amdgcn_sqrtf(fmaf(ex0, ex0, ey0 * ey0)), EVF);
            const float num = fmaf(ex0 * ex0, eyy,
                              fmaf(-2.0f * ex0 * ey0, exy, ey0 * ey0 * exx));
            const float kabs = fabsf(num) * __builtin_amdgcn_rcpf(ev * ev * ev);

            const float aw = fabsf(eg(eps, n, i, j) + 1e-6f);
            const float mx = fmaxf(ev, aw);
            const float mn = fminf(ev, aw);
            const float t  = mn * __builtin_amdgcn_rcpf(mx);
            const float t2 = t * t;
            float pl = fmaf(t2, -0.01172120f, 0.05265332f);
            pl = fmaf(t2, pl, -0.11643287f);
            pl = fmaf(t2, pl, 0.19354346f);
            pl = fmaf(t2, pl, -0.33262347f);
            pl = fmaf(t2, pl, 0.99997726f);
            pl *= t;
            const float at = (ev > aw) ? (PIH - pl) : pl;

            acc += fmaxf(fmaf(kabs, at, -PID), 0.0f);
        }
    }

    // ================= inner (central-difference) strip ====================
    {
        const int gg = blockIdx.x * 256 + threadIdx.x;     // col group id
        const bool valid = gg < G2;
        const int gc = min(gg, G2 - 1);
        // thread owns cols 4gc+2..4gc+5; loads [4gc, 4gc+8) — 16B aligned
        const int i0 = 2 + RS * blockIdx.y;
        const int count = min(RS, (n - 2) - i0);           // even by constr.
        const float*  pj = eps + 4 * (size_t)gc;
        const size_t  sn = (size_t)n;
        const f2 inv2d2  = mk(inv_2d, inv_2d);
        const f2 inv4dd2 = mk(inv_4dd, inv_4dd);

        Row s0, s1, s2, s3, s4, s5, s6, s7;
        load_row(s0, pj + (size_t)(i0 - 2) * sn);
        load_row(s1, pj + (size_t)(i0 - 1) * sn);
        load_row(s2, pj + (size_t)(i0    ) * sn);
        load_row(s3, pj + (size_t)(i0 + 1) * sn);
        load_row(s4, pj + (size_t)(i0 + 2) * sn);
        load_row(s5, pj + (size_t)(i0 + 3) * sn);
        const float* pnext = pj + (size_t)(i0 + 4) * sn;

        f2 acc2 = mk(0.0f, 0.0f);
        #define PHASEP(ph, A0, A1, A2, A3, A4, A5, L0, L1)                    \
        {                                                                     \
            const int k = kbase + 2 * (ph);                                   \
            if (k < count) {                                                  \
                if (k + 2 < count) {                                          \
                    load_row(L0, pnext);                                      \
                    load_row(L1, pnext + sn);                                 \
                }                                                             \
                pnext += 2 * sn;                                              \
                acc2 = acc2 + compute_pair(A0, A1, A2, A3, A4, A5,            \
                                           inv2d2, inv4dd2);                  \
            }                                                                 \
        }

        #pragma unroll 1
        for (int kbase = 0; kbase < RS; kbase += 8) {
            PHASEP(0, s0, s1, s2, s3, s4, s5, s6, s7)
            PHASEP(1, s2, s3, s4, s5, s6, s7, s0, s1)
            PHASEP(2, s4, s5, s6, s7, s0, s1, s2, s3)
            PHASEP(3, s6, s7, s0, s1, s2, s3, s4, s5)
        }
        #undef PHASEP

        if (valid) acc += acc2.x + acc2.y;
    }

    // ---- reduction: wave -> block (LDS) -> scattered ws atomics ----
    __shared__ float wsum[4];
    #pragma unroll
    for (int off = 32; off; off >>= 1)
        acc += __shfl_down(acc, off, 64);
    if ((threadIdx.x & 63) == 0) wsum[threadIdx.x >> 6] = acc;
    __syncthreads();
    if (threadIdx.x == 0) {
        const int slot = (blockIdx.y * gridDim.x + blockIdx.x) & 63;
        atomicAdd(&ws[slot], wsum[0] + wsum[1] + wsum[2] + wsum[3]);
    }
}

__global__ __launch_bounds__(64)
void fab_finish(const float* __restrict__ ws, const float* __restrict__ gs,
                float* __restrict__ out) {
    const float d = *gs;
    float v = ws[threadIdx.x];
    #pragma unroll
    for (int off = 32; off; off >>= 1)
        v += __shfl_down(v, off, 64);
    if (threadIdx.x == 0) out[0] = v * d * d;
}

extern "C" void kernel_launch(void* const* d_in, const int* in_sizes, int n_in,
                              void* d_out, int out_size, void* d_ws, size_t ws_size,
                              hipStream_t stream) {
    const float* eps = (const float*)d_in[0];
    const float* gs  = (const float*)d_in[1];
    float* out = (float*)d_out;
    float* ws  = (float*)d_ws;

    const long long tot = (long long)in_sizes[0];
    const int n = (int)(sqrt((double)tot) + 0.5);   // 8192

    hipMemsetAsync(ws, 0, 64 * sizeof(float), stream);

    const int G2  = (n - 8) / 4;                    // 2046 interior col groups
    const int nstrip = (n - 4 + RS - 1) / RS;       // 128
    const int nfr = 4 * n + 8 * (n - 4);            // frame element count

    dim3 block(256, 1);
    dim3 grid(n / 1024, nstrip);                    // 8 x 128 = 1024 blocks
    fab_fused<<<grid, block, 0, stream>>>(eps, gs, ws, n, G2, nfr);
    fab_finish<<<1, 64, 0, stream>>>(ws, gs, out);
}

// Round 9
// 90.465 us; speedup vs baseline: 1.0442x; 1.0442x over previous
//
#include <hip/hip_runtime.h>
#include <math.h>

// Fused fab_penalty_ls_curve: 13-point stencil over eps + global reduction.
// R8 post-mortem: alignment/rsq/atomic micro-fixes flat-to-negative. But
// cross-config: time ~ inst/el across LDS (R2: 103 inst, 285us) and reg
// (R5: ~37 inst, 92us) structures => issue-bound. R9: algebraic factoring —
// raw-diff stencil units, all d-scalings folded into c1=inv2d, c2=1e16*inv2d^4:
//   kabs = |N| * min(c1*rsq(r2)^3, c2),  ev = max(c1*r2*rsq, EVF)
// (drops 3 inv4dd muls, 2 SC adds, 2 inv2d muls per element; exact w.r.t.
// the EVF floor; SC drop safe: identical result at exact-zero gradients).
// Also: no memset (blocks store partials to distinct ws slots), prologue
// loads issued before frame work.

typedef float f2 __attribute__((ext_vector_type(2)));
typedef float f4 __attribute__((ext_vector_type(4)));   // 16B-aligned

constexpr float SCF = 1e-12f;
constexpr float EVF = 4.6415888336e-6f;        // 1e-32^(1/6); EVF^3 = 1e-16
constexpr float PID = 2.8559933214452666f;     // pi/1.1
constexpr float PIH = 1.5707963268f;
constexpr int   RS  = 64;                      // rows per strip (mult of 8)

struct Row { f4 lo, hi; };                     // cols 4g..4g+3, 4g+4..4g+7

__device__ __forceinline__ float C(const Row& r, int k) {
    return k < 4 ? r.lo[k] : r.hi[k - 4];      // col 4g+k = j-2+k (j=4g+2)
}
__device__ __forceinline__ void load_row(Row& r, const float* p) {
    r.lo = *(const f4*)p;                      // aligned dwordx4
    r.hi = *(const f4*)(p + 4);                // aligned dwordx4
}
__device__ __forceinline__ f2 mk(float a, float b) { f2 v; v.x = a; v.y = b; return v; }
__device__ __forceinline__ f2 fma2(f2 a, f2 b, f2 c) { return __builtin_elementwise_fma(a, b, c); }
__device__ __forceinline__ f2 max2(f2 a, f2 b) { return __builtin_elementwise_max(a, b); }
__device__ __forceinline__ f2 min2(f2 a, f2 b) { return __builtin_elementwise_min(a, b); }
__device__ __forceinline__ f2 abs2(f2 a) { return __builtin_elementwise_abs(a); }
__device__ __forceinline__ f2 rcp2(f2 a) {
    return mk(__builtin_amdgcn_rcpf(a.x), __builtin_amdgcn_rcpf(a.y));
}
__device__ __forceinline__ f2 rsq2(f2 a) {
    return mk(__builtin_amdgcn_rsqf(a.x), __builtin_amdgcn_rsqf(a.y));
}

// ---- packed factored math for output rows (i, i+1): R0..R5 = rows i-2..i+3
// c1 = inv2d ; c2 = 1e16 * inv2d^4
__device__ __forceinline__ f2 compute_pair(const Row& R0, const Row& R1,
                                           const Row& R2, const Row& R3,
                                           const Row& R4, const Row& R5,
                                           f2 c1, f2 c2) {
    f2 dif[6];                                 // raw row diffs at cols j-1..j+4
    #pragma unroll
    for (int k = 0; k < 6; ++k)
        dif[k] = mk(C(R3, k + 1) - C(R1, k + 1),
                    C(R4, k + 1) - C(R2, k + 1));
    f2 Pz[8];                                  // center rows, cols j-2..j+5
    #pragma unroll
    for (int k = 0; k < 8; ++k)
        Pz[k] = mk(C(R2, k), C(R3, k));

    f2 part = mk(0.0f, 0.0f);
    #pragma unroll
    for (int q = 0; q < 4; ++q) {
        const f2 c00  = Pz[q + 2];
        const f2 u    = dif[q + 1];                      // raw d/di * 2d
        const f2 v    = Pz[q + 3] - Pz[q + 1];           // raw d/dj * 2d
        const f2 exxr = fma2(mk(-2.0f, -2.0f), c00,
                             mk(C(R4, q + 2) + C(R0, q + 2),
                                C(R5, q + 2) + C(R1, q + 2)));
        const f2 eyyr = fma2(mk(-2.0f, -2.0f), c00, Pz[q + 4] + Pz[q]);
        const f2 exyr = dif[q + 2] - dif[q];

        const f2 uu  = u * u;
        const f2 vv  = v * v;
        const f2 r2  = uu + vv;
        const f2 rsq = rsq2(r2);
        const f2 N   = fma2(uu, eyyr, fma2(-2.0f * (u * v), exyr, vv * exxr));
        const f2 r3  = rsq * rsq * rsq;
        const f2 kabs = abs2(N) * min2(c1 * r3, c2);
        const f2 ev   = max2(c1 * (r2 * rsq), mk(EVF, EVF)); // NaN@r2=0 -> EVF

        // |atan(ev/w)| = atan(ev/|w|): min/max range reduction, 1 rcp
        const f2 aw = abs2(c00 + 1e-6f);
        const f2 mx = max2(ev, aw);
        const f2 mn = min2(ev, aw);
        const f2 t  = mn * rcp2(mx);
        const f2 t2 = t * t;
        f2 pl = fma2(t2, mk(-0.01172120f, -0.01172120f), mk(0.05265332f, 0.05265332f));
        pl = fma2(t2, pl, mk(-0.11643287f, -0.11643287f));
        pl = fma2(t2, pl, mk(0.19354346f, 0.19354346f));
        pl = fma2(t2, pl, mk(-0.33262347f, -0.33262347f));
        pl = fma2(t2, pl, mk(0.99997726f, 0.99997726f));
        pl = pl * t;
        f2 at;
        at.x = (ev.x > aw.x) ? PIH - pl.x : pl.x;
        at.y = (ev.y > aw.y) ? PIH - pl.y : pl.y;

        // max(NaN,0)=0 implements nansum
        part = part + max2(fma2(kabs, at, mk(-PID, -PID)), mk(0.0f, 0.0f));
    }
    return part;
}

// ---- frame-path helpers: numpy edge_order=1 gradients on global memory ----
__device__ __forceinline__ float eg(const float* __restrict__ e, int n, int i, int j) {
    return e[(size_t)i * (size_t)n + j];
}
__device__ __forceinline__ float gex(const float* __restrict__ e, int n, int i, int j,
                                     float inv_d, float inv_2d) {
    float v;
    if (i == 0)          v = (eg(e, n, 1, j) - eg(e, n, 0, j)) * inv_d;
    else if (i == n - 1) v = (eg(e, n, n - 1, j) - eg(e, n, n - 2, j)) * inv_d;
    else                 v = (eg(e, n, i + 1, j) - eg(e, n, i - 1, j)) * inv_2d;
    return v + SCF;
}
__device__ __forceinline__ float gey(const float* __restrict__ e, int n, int i, int j,
                                     float inv_d, float inv_2d) {
    float v;
    if (j == 0)          v = (eg(e, n, i, 1) - eg(e, n, i, 0)) * inv_d;
    else if (j == n - 1) v = (eg(e, n, i, n - 1) - eg(e, n, i, n - 2)) * inv_d;
    else                 v = (eg(e, n, i, j + 1) - eg(e, n, i, j - 1)) * inv_2d;
    return v + SCF;
}

__global__ __launch_bounds__(256, 4)
void fab_fused(const float* __restrict__ eps, const float* __restrict__ gs,
               float* __restrict__ ws, int n, int G2, int nfr) {
    const float d      = *gs;
    const float inv_2d = 0.5f / d;
    const float c1s    = inv_2d;
    const float c2s    = 1e16f * (inv_2d * inv_2d) * (inv_2d * inv_2d);

    float acc = 0.0f;

    // ---- strip setup + prologue loads issued FIRST (latency hides under
    //      the frame work below) ----
    const int gg = blockIdx.x * 256 + threadIdx.x;     // col group id
    const bool valid = gg < G2;
    const int gc = min(gg, G2 - 1);
    const int i0 = 2 + RS * blockIdx.y;
    const int count = min(RS, (n - 2) - i0);           // even by construction
    const float*  pj = eps + 4 * (size_t)gc;           // 16B-aligned windows
    const size_t  sn = (size_t)n;

    Row s0, s1, s2, s3, s4, s5, s6, s7;
    load_row(s0, pj + (size_t)(i0 - 2) * sn);
    load_row(s1, pj + (size_t)(i0 - 1) * sn);
    load_row(s2, pj + (size_t)(i0    ) * sn);
    load_row(s3, pj + (size_t)(i0 + 1) * sn);
    load_row(s4, pj + (size_t)(i0 + 2) * sn);
    load_row(s5, pj + (size_t)(i0 + 3) * sn);
    const float* pnext = pj + (size_t)(i0 + 4) * sn;

    // ========== frame (edge_order=1 one-sided) — 96 elements/block =========
    if (threadIdx.x < 96) {
        const int bflat = blockIdx.y * gridDim.x + blockIdx.x;
        const int idx = bflat * 96 + (int)threadIdx.x;
        if (idx < nfr) {
            const float inv_d = inv_2d + inv_2d;
            int i, j;
            if (idx < 4 * n) {
                const int rr = (idx >= n) + (idx >= 2 * n) + (idx >= 3 * n);
                j = idx - rr * n;
                i = (rr < 2) ? rr : (n - 4) + rr;             // 0,1,n-2,n-1
            } else {
                const int t = idx - 4 * n;
                i = 2 + (t >> 3);                             // rows 2..n-3
                const int cc = t & 7;
                j = (cc < 2) ? cc : (n - 8) + cc;             // 0,1, n-6..n-1
            }

            const float ex0 = gex(eps, n, i, j, inv_d, inv_2d);
            const float ey0 = gey(eps, n, i, j, inv_d, inv_2d);

            float exx, exy, eyy;
            if (i == 0)
                exx = (gex(eps, n, 1, j, inv_d, inv_2d) - ex0) * inv_d;
            else if (i == n - 1)
                exx = (ex0 - gex(eps, n, n - 2, j, inv_d, inv_2d)) * inv_d;
            else
                exx = (gex(eps, n, i + 1, j, inv_d, inv_2d)
                     - gex(eps, n, i - 1, j, inv_d, inv_2d)) * inv_2d;

            if (j == 0)
                exy = (gex(eps, n, i, 1, inv_d, inv_2d) - ex0) * inv_d;
            else if (j == n - 1)
                exy = (ex0 - gex(eps, n, i, n - 2, inv_d, inv_2d)) * inv_d;
            else
                exy = (gex(eps, n, i, j + 1, inv_d, inv_2d)
                     - gex(eps, n, i, j - 1, inv_d, inv_2d)) * inv_2d;

            if (j == 0)
                eyy = (gey(eps, n, i, 1, inv_d, inv_2d) - ey0) * inv_d;
            else if (j == n - 1)
                eyy = (ey0 - gey(eps, n, i, n - 2, inv_d, inv_2d)) * inv_d;
            else
                eyy = (gey(eps, n, i, j + 1, inv_d, inv_2d)
                     - gey(eps, n, i, j - 1, inv_d, inv_2d)) * inv_2d;

            const float ev = fmaxf(__builtin_amdgcn_sqrtf(fmaf(ex0, ex0, ey0 * ey0)), EVF);
            const float num = fmaf(ex0 * ex0, eyy,
                              fmaf(-2.0f * ex0 * ey0, exy, ey0 * ey0 * exx));
            const float kabs = fabsf(num) * __builtin_amdgcn_rcpf(ev * ev * ev);

            const float aw = fabsf(eg(eps, n, i, j) + 1e-6f);
            const float mx = fmaxf(ev, aw);
            const float mn = fminf(ev, aw);
            const float t  = mn * __builtin_amdgcn_rcpf(mx);
            const float t2 = t * t;
            float pl = fmaf(t2, -0.01172120f, 0.05265332f);
            pl = fmaf(t2, pl, -0.11643287f);
            pl = fmaf(t2, pl, 0.19354346f);
            pl = fmaf(t2, pl, -0.33262347f);
            pl = fmaf(t2, pl, 0.99997726f);
            pl *= t;
            const float at = (ev > aw) ? (PIH - pl) : pl;

            acc += fmaxf(fmaf(kabs, at, -PID), 0.0f);
        }
    }

    // ================= inner (central-difference) strip ====================
    {
        const f2 c1 = mk(c1s, c1s);
        const f2 c2 = mk(c2s, c2s);

        f2 acc2 = mk(0.0f, 0.0f);
        #define PHASEP(ph, A0, A1, A2, A3, A4, A5, L0, L1)                    \
        {                                                                     \
            const int k = kbase + 2 * (ph);                                   \
            if (k < count) {                                                  \
                if (k + 2 < count) {                                          \
                    load_row(L0, pnext);                                      \
                    load_row(L1, pnext + sn);                                 \
                }                                                             \
                pnext += 2 * sn;                                              \
                acc2 = acc2 + compute_pair(A0, A1, A2, A3, A4, A5, c1, c2);   \
            }                                                                 \
        }

        #pragma unroll 1
        for (int kbase = 0; kbase < RS; kbase += 8) {
            PHASEP(0, s0, s1, s2, s3, s4, s5, s6, s7)
            PHASEP(1, s2, s3, s4, s5, s6, s7, s0, s1)
            PHASEP(2, s4, s5, s6, s7, s0, s1, s2, s3)
            PHASEP(3, s6, s7, s0, s1, s2, s3, s4, s5)
        }
        #undef PHASEP

        if (valid) acc += acc2.x + acc2.y;
    }

    // ---- reduction: wave -> block (LDS) -> plain store to unique slot ----
    __shared__ float wsum[4];
    #pragma unroll
    for (int off = 32; off; off >>= 1)
        acc += __shfl_down(acc, off, 64);
    if ((threadIdx.x & 63) == 0) wsum[threadIdx.x >> 6] = acc;
    __syncthreads();
    if (threadIdx.x == 0)
        ws[blockIdx.y * gridDim.x + blockIdx.x] =
            wsum[0] + wsum[1] + wsum[2] + wsum[3];
}

__global__ __launch_bounds__(256)
void fab_finish(const float* __restrict__ ws, const float* __restrict__ gs,
                float* __restrict__ out, int nb) {
    __shared__ float wsum[4];
    float v = 0.0f;
    for (int i = threadIdx.x; i < nb; i += 256) v += ws[i];
    #pragma unroll
    for (int off = 32; off; off >>= 1)
        v += __shfl_down(v, off, 64);
    if ((threadIdx.x & 63) == 0) wsum[threadIdx.x >> 6] = v;
    __syncthreads();
    if (threadIdx.x == 0) {
        const float d = *gs;
        out[0] = (wsum[0] + wsum[1] + wsum[2] + wsum[3]) * d * d;
    }
}

extern "C" void kernel_launch(void* const* d_in, const int* in_sizes, int n_in,
                              void* d_out, int out_size, void* d_ws, size_t ws_size,
                              hipStream_t stream) {
    const float* eps = (const float*)d_in[0];
    const float* gs  = (const float*)d_in[1];
    float* out = (float*)d_out;
    float* ws  = (float*)d_ws;

    const long long tot = (long long)in_sizes[0];
    const int n = (int)(sqrt((double)tot) + 0.5);   // 8192

    const int G2  = (n - 8) / 4;                    // 2046 interior col groups
    const int nstrip = (n - 4 + RS - 1) / RS;       // 128
    const int nfr = 4 * n + 8 * (n - 4);            // frame element count

    dim3 block(256, 1);
    dim3 grid(n / 1024, nstrip);                    // 8 x 128 = 1024 blocks
    fab_fused<<<grid, block, 0, stream>>>(eps, gs, ws, n, G2, nfr);
    fab_finish<<<1, 256, 0, stream>>>(ws, gs, out, grid.x * grid.y);
}

// Round 10
// 85.289 us; speedup vs baseline: 1.1076x; 1.0607x over previous
//
#include <hip/hip_runtime.h>
#include <math.h>

// Fused fab_penalty_ls_curve: 13-point stencil over eps + global reduction.
// R9 post-mortem: -12% instructions -> -2% time. Decomposition: VALU-exec
// ~38us + mem ~50us ~= 90us observed, SIMD busy ~35% => pipes SERIALIZED by
// phase-lock (all waves identical stream, capacity-exact launch: everyone
// loads together, then computes together). Plus frame path: stride-n
// uncoalesced loads => ~65MB extra fetch in every block.
// R10: (1) stagger each block's row sweep by 16*(bflat&3) rows (cyclic, two
// segments) to interleave load/compute bursts across co-resident waves;
// (2) frame edge-cols reworked to one ROW per lane with 15 dwordx4 into a
// 5x12 register window (fetch 65MB -> ~8MB), 40 tasks/block on wave 0.

typedef float f2 __attribute__((ext_vector_type(2)));
typedef float f4 __attribute__((ext_vector_type(4)));

constexpr float SCF = 1e-12f;
constexpr float EVF = 4.6415888336e-6f;        // 1e-32^(1/6)
constexpr float PID = 2.8559933214452666f;     // pi/1.1
constexpr float PIH = 1.5707963268f;
constexpr int   RS  = 64;                      // rows per strip
constexpr int   FT  = 40;                      // frame tasks per block

struct Row { f4 lo, hi; };                     // cols 4g..4g+3, 4g+4..4g+7

__device__ __forceinline__ float C(const Row& r, int k) {
    return k < 4 ? r.lo[k] : r.hi[k - 4];
}
__device__ __forceinline__ void load_row(Row& r, const float* p) {
    r.lo = *(const f4*)p;
    r.hi = *(const f4*)(p + 4);
}
__device__ __forceinline__ f2 mk(float a, float b) { f2 v; v.x = a; v.y = b; return v; }
__device__ __forceinline__ f2 fma2(f2 a, f2 b, f2 c) { return __builtin_elementwise_fma(a, b, c); }
__device__ __forceinline__ f2 max2(f2 a, f2 b) { return __builtin_elementwise_max(a, b); }
__device__ __forceinline__ f2 min2(f2 a, f2 b) { return __builtin_elementwise_min(a, b); }
__device__ __forceinline__ f2 abs2(f2 a) { return __builtin_elementwise_abs(a); }
__device__ __forceinline__ f2 rcp2(f2 a) {
    return mk(__builtin_amdgcn_rcpf(a.x), __builtin_amdgcn_rcpf(a.y));
}
__device__ __forceinline__ f2 rsq2(f2 a) {
    return mk(__builtin_amdgcn_rsqf(a.x), __builtin_amdgcn_rsqf(a.y));
}

// ---- packed factored math for output rows (i,i+1): R0..R5 = rows i-2..i+3
__device__ __forceinline__ f2 compute_pair(const Row& R0, const Row& R1,
                                           const Row& R2, const Row& R3,
                                           const Row& R4, const Row& R5,
                                           f2 c1, f2 c2) {
    f2 dif[6];
    #pragma unroll
    for (int k = 0; k < 6; ++k)
        dif[k] = mk(C(R3, k + 1) - C(R1, k + 1),
                    C(R4, k + 1) - C(R2, k + 1));
    f2 Pz[8];
    #pragma unroll
    for (int k = 0; k < 8; ++k)
        Pz[k] = mk(C(R2, k), C(R3, k));

    f2 part = mk(0.0f, 0.0f);
    #pragma unroll
    for (int q = 0; q < 4; ++q) {
        const f2 c00  = Pz[q + 2];
        const f2 u    = dif[q + 1];
        const f2 v    = Pz[q + 3] - Pz[q + 1];
        const f2 exxr = fma2(mk(-2.0f, -2.0f), c00,
                             mk(C(R4, q + 2) + C(R0, q + 2),
                                C(R5, q + 2) + C(R1, q + 2)));
        const f2 eyyr = fma2(mk(-2.0f, -2.0f), c00, Pz[q + 4] + Pz[q]);
        const f2 exyr = dif[q + 2] - dif[q];

        const f2 uu  = u * u;
        const f2 vv  = v * v;
        const f2 r2  = uu + vv;
        const f2 rsq = rsq2(r2);
        const f2 N   = fma2(uu, eyyr, fma2(-2.0f * (u * v), exyr, vv * exxr));
        const f2 r3  = rsq * rsq * rsq;
        const f2 kabs = abs2(N) * min2(c1 * r3, c2);
        const f2 ev   = max2(c1 * (r2 * rsq), mk(EVF, EVF));

        const f2 aw = abs2(c00 + 1e-6f);
        const f2 mx = max2(ev, aw);
        const f2 mn = min2(ev, aw);
        const f2 t  = mn * rcp2(mx);
        const f2 t2 = t * t;
        f2 pl = fma2(t2, mk(-0.01172120f, -0.01172120f), mk(0.05265332f, 0.05265332f));
        pl = fma2(t2, pl, mk(-0.11643287f, -0.11643287f));
        pl = fma2(t2, pl, mk(0.19354346f, 0.19354346f));
        pl = fma2(t2, pl, mk(-0.33262347f, -0.33262347f));
        pl = fma2(t2, pl, mk(0.99997726f, 0.99997726f));
        pl = pl * t;
        f2 at;
        at.x = (ev.x > aw.x) ? PIH - pl.x : pl.x;
        at.y = (ev.y > aw.y) ? PIH - pl.y : pl.y;

        part = part + max2(fma2(kabs, at, mk(-PID, -PID)), mk(0.0f, 0.0f));
    }
    return part;
}

// ---- scalar tail (frame) ----
__device__ __forceinline__ float penalty_scalar(float ex, float ey, float exx,
                                                float exy, float eyy, float w) {
    const float ev = fmaxf(__builtin_amdgcn_sqrtf(fmaf(ex, ex, ey * ey)), EVF);
    const float num = fmaf(ex * ex, eyy, fmaf(-2.0f * ex * ey, exy, ey * ey * exx));
    const float kabs = fabsf(num) * __builtin_amdgcn_rcpf(ev * ev * ev);
    const float aw = fabsf(w + 1e-6f);
    const float mx = fmaxf(ev, aw);
    const float mn = fminf(ev, aw);
    const float t  = mn * __builtin_amdgcn_rcpf(mx);
    const float t2 = t * t;
    float pl = fmaf(t2, -0.01172120f, 0.05265332f);
    pl = fmaf(t2, pl, -0.11643287f);
    pl = fmaf(t2, pl, 0.19354346f);
    pl = fmaf(t2, pl, -0.33262347f);
    pl = fmaf(t2, pl, 0.99997726f);
    pl *= t;
    const float at = (ev > aw) ? (PIH - pl) : pl;
    return fmaxf(fmaf(kabs, at, -PID), 0.0f);
}

// ---- global-memory edge_order=1 gradients (top/bottom rows only) ----
__device__ __forceinline__ float eg(const float* __restrict__ e, int n, int i, int j) {
    return e[(size_t)i * (size_t)n + j];
}
__device__ __forceinline__ float gex(const float* __restrict__ e, int n, int i, int j,
                                     float inv_d, float inv_2d) {
    float v;
    if (i == 0)          v = (eg(e, n, 1, j) - eg(e, n, 0, j)) * inv_d;
    else if (i == n - 1) v = (eg(e, n, n - 1, j) - eg(e, n, n - 2, j)) * inv_d;
    else                 v = (eg(e, n, i + 1, j) - eg(e, n, i - 1, j)) * inv_2d;
    return v + SCF;
}
__device__ __forceinline__ float gey(const float* __restrict__ e, int n, int i, int j,
                                     float inv_d, float inv_2d) {
    float v;
    if (j == 0)          v = (eg(e, n, i, 1) - eg(e, n, i, 0)) * inv_d;
    else if (j == n - 1) v = (eg(e, n, i, n - 1) - eg(e, n, i, n - 2)) * inv_d;
    else                 v = (eg(e, n, i, j + 1) - eg(e, n, i, j - 1)) * inv_2d;
    return v + SCF;
}

__global__ __launch_bounds__(256, 4)
void fab_fused(const float* __restrict__ eps, const float* __restrict__ gs,
               float* __restrict__ ws, int n, int G2) {
    const float d      = *gs;
    const float inv_2d = 0.5f / d;
    const float inv_d  = inv_2d + inv_2d;
    const float c1s    = inv_2d;
    const float c2s    = 1e16f * (inv_2d * inv_2d) * (inv_2d * inv_2d);
    const int bflat    = blockIdx.y * gridDim.x + blockIdx.x;

    float acc = 0.0f;

    // ================== frame: 40 tasks/block on wave 0 ====================
    if (threadIdx.x < FT) {
        const int t = bflat * FT + (int)threadIdx.x;
        const int ntop = 4 * n;
        if (t < ntop) {
            // rows {0,1,n-2,n-1} x all cols — coalesced scalar path
            const int rr = (t >= n) + (t >= 2 * n) + (t >= 3 * n);
            const int j = t - rr * n;
            const int i = (rr < 2) ? rr : (n - 4) + rr;

            const float ex0 = gex(eps, n, i, j, inv_d, inv_2d);
            const float ey0 = gey(eps, n, i, j, inv_d, inv_2d);
            float exx, exy, eyy;
            if (i == 0)
                exx = (gex(eps, n, 1, j, inv_d, inv_2d) - ex0) * inv_d;
            else if (i == n - 1)
                exx = (ex0 - gex(eps, n, n - 2, j, inv_d, inv_2d)) * inv_d;
            else
                exx = (gex(eps, n, i + 1, j, inv_d, inv_2d)
                     - gex(eps, n, i - 1, j, inv_d, inv_2d)) * inv_2d;
            if (j == 0)
                exy = (gex(eps, n, i, 1, inv_d, inv_2d) - ex0) * inv_d;
            else if (j == n - 1)
                exy = (ex0 - gex(eps, n, i, n - 2, inv_d, inv_2d)) * inv_d;
            else
                exy = (gex(eps, n, i, j + 1, inv_d, inv_2d)
                     - gex(eps, n, i, j - 1, inv_d, inv_2d)) * inv_2d;
            if (j == 0)
                eyy = (gey(eps, n, i, 1, inv_d, inv_2d) - ey0) * inv_d;
            else if (j == n - 1)
                eyy = (ey0 - gey(eps, n, i, n - 2, inv_d, inv_2d)) * inv_d;
            else
                eyy = (gey(eps, n, i, j + 1, inv_d, inv_2d)
                     - gey(eps, n, i, j - 1, inv_d, inv_2d)) * inv_2d;

            acc += penalty_scalar(ex0, ey0, exx, exy, eyy, eg(eps, n, i, j));
        } else if (t < ntop + (n - 4)) {
            // edge cols {0,1, n-6..n-1} of row i — one row per lane,
            // 15 dwordx4 into a 5x12 register window (coalesced per lane).
            const int i = 2 + (t - ntop);               // i in [2, n-3]
            float W[5][12];
            const float* rb = eps + (size_t)(i - 2) * (size_t)n;
            #pragma unroll
            for (int r = 0; r < 5; ++r) {
                const f4 a = *(const f4*)(rb + (size_t)r * n);            // cols 0..3
                const f4 b = *(const f4*)(rb + (size_t)r * n + (n - 8));  // n-8..n-5
                const f4 c = *(const f4*)(rb + (size_t)r * n + (n - 4));  // n-4..n-1
                #pragma unroll
                for (int k = 0; k < 4; ++k) {
                    W[r][k] = a[k]; W[r][4 + k] = b[k]; W[r][8 + k] = c[k];
                }
            }
            // wc: 0..3 = cols 0..3 ; 4..11 = cols n-8..n-1
            auto exW = [&](int r, int wc) {
                return (W[r + 1][wc] - W[r - 1][wc]) * inv_2d + SCF;
            };
            auto eyW = [&](int wc) {   // center row (r=2)
                if (wc == 0)  return (W[2][1] - W[2][0]) * inv_d + SCF;
                if (wc == 11) return (W[2][11] - W[2][10]) * inv_d + SCF;
                return (W[2][wc + 1] - W[2][wc - 1]) * inv_2d + SCF;
            };
            #pragma unroll
            for (int m = 0; m < 8; ++m) {
                const int wc = (m < 2) ? m : m + 4;      // {0,1,6..11}
                const float ex0 = exW(2, wc);
                const float ey0 = eyW(wc);
                const float exx = (exW(3, wc) - exW(1, wc)) * inv_2d;
                float exy, eyy;
                if (wc == 0) {
                    exy = (exW(2, 1) - exW(2, 0)) * inv_d;
                    eyy = (eyW(1) - eyW(0)) * inv_d;
                } else if (wc == 11) {
                    exy = (exW(2, 11) - exW(2, 10)) * inv_d;
                    eyy = (eyW(11) - eyW(10)) * inv_d;
                } else {
                    exy = (exW(2, wc + 1) - exW(2, wc - 1)) * inv_2d;
                    eyy = (eyW(wc + 1) - eyW(wc - 1)) * inv_2d;
                }
                acc += penalty_scalar(ex0, ey0, exx, exy, eyy, W[2][wc]);
            }
        }
    }

    // ================= inner strip, staggered two-segment sweep ============
    {
        const int gg = blockIdx.x * 256 + threadIdx.x;
        const bool valid = gg < G2;
        const int gc = min(gg, G2 - 1);
        const int i0 = 2 + RS * blockIdx.y;
        const int count = min(RS, (n - 2) - i0);        // 64 or 60, even
        const float* pj = eps + 4 * (size_t)gc;         // 16B-aligned windows
        const size_t sn = (size_t)n;
        const f2 c1 = mk(c1s, c1s);
        const f2 c2 = mk(c2s, c2s);

        f2 acc2 = mk(0.0f, 0.0f);

        auto sweep = [&](int start, int len) {
            Row s0, s1, s2, s3, s4, s5, s6, s7;
            load_row(s0, pj + (size_t)(start - 2) * sn);
            load_row(s1, pj + (size_t)(start - 1) * sn);
            load_row(s2, pj + (size_t)(start    ) * sn);
            load_row(s3, pj + (size_t)(start + 1) * sn);
            load_row(s4, pj + (size_t)(start + 2) * sn);
            load_row(s5, pj + (size_t)(start + 3) * sn);
            const float* pnext = pj + (size_t)(start + 4) * sn;

            #define PHASEP(ph, A0, A1, A2, A3, A4, A5, L0, L1)                \
            {                                                                 \
                const int k = kbase + 2 * (ph);                               \
                if (k < len) {                                                \
                    if (k + 2 < len) {                                        \
                        load_row(L0, pnext);                                  \
                        load_row(L1, pnext + sn);                             \
                    }                                                         \
                    pnext += 2 * sn;                                          \
                    acc2 = acc2 + compute_pair(A0, A1, A2, A3, A4, A5,        \
                                               c1, c2);                       \
                }                                                             \
            }
            #pragma unroll 1
            for (int kbase = 0; kbase < len; kbase += 8) {
                PHASEP(0, s0, s1, s2, s3, s4, s5, s6, s7)
                PHASEP(1, s2, s3, s4, s5, s6, s7, s0, s1)
                PHASEP(2, s4, s5, s6, s7, s0, s1, s2, s3)
                PHASEP(3, s6, s7, s0, s1, s2, s3, s4, s5)
            }
            #undef PHASEP
        };

        const int off = 16 * (bflat & 3);               // 0,16,32,48 < count
        sweep(i0 + off, count - off);
        if (off > 0) sweep(i0, off);

        if (valid) acc += acc2.x + acc2.y;
    }

    // ---- reduction: wave -> block (LDS) -> unique ws slot ----
    __shared__ float wsum[4];
    #pragma unroll
    for (int off = 32; off; off >>= 1)
        acc += __shfl_down(acc, off, 64);
    if ((threadIdx.x & 63) == 0) wsum[threadIdx.x >> 6] = acc;
    __syncthreads();
    if (threadIdx.x == 0)
        ws[bflat] = wsum[0] + wsum[1] + wsum[2] + wsum[3];
}

__global__ __launch_bounds__(256)
void fab_finish(const float* __restrict__ ws, const float* __restrict__ gs,
                float* __restrict__ out, int nb) {
    __shared__ float wsum[4];
    float v = 0.0f;
    for (int i = threadIdx.x; i < nb; i += 256) v += ws[i];
    #pragma unroll
    for (int off = 32; off; off >>= 1)
        v += __shfl_down(v, off, 64);
    if ((threadIdx.x & 63) == 0) wsum[threadIdx.x >> 6] = v;
    __syncthreads();
    if (threadIdx.x == 0) {
        const float d = *gs;
        out[0] = (wsum[0] + wsum[1] + wsum[2] + wsum[3]) * d * d;
    }
}

extern "C" void kernel_launch(void* const* d_in, const int* in_sizes, int n_in,
                              void* d_out, int out_size, void* d_ws, size_t ws_size,
                              hipStream_t stream) {
    const float* eps = (const float*)d_in[0];
    const float* gs  = (const float*)d_in[1];
    float* out = (float*)d_out;
    float* ws  = (float*)d_ws;

    const long long tot = (long long)in_sizes[0];
    const int n = (int)(sqrt((double)tot) + 0.5);   // 8192

    const int G2 = (n - 8) / 4;                     // interior col groups
    const int nstrip = (n - 4 + RS - 1) / RS;       // 128

    dim3 block(256, 1);
    dim3 grid(n / 1024, nstrip);                    // 8 x 128 = 1024 blocks
    fab_fused<<<grid, block, 0, stream>>>(eps, gs, ws, n, G2);
    fab_finish<<<1, 256, 0, stream>>>(ws, gs, out, grid.x * grid.y);
}

// Round 11
// 85.229 us; speedup vs baseline: 1.1084x; 1.0007x over previous
//
#include <hip/hip_runtime.h>
#include <math.h>

// Fused fab_penalty_ls_curve: 13-point stencil over eps + global reduction.
// R10 post-mortem: -6% but entirely from frame coalescing; the stagger used
// bflat&3 while same-CU blocks are {c, c+256, c+512, c+768} (round-robin) --
// identical offsets, so waves stayed phase-locked. Theory untested.
// R11: per-WAVE stagger: off = 16*((waveid + bflat + (bflat>>8)) & 3).
// The 4 waves on each SIMD (and in each block) now sweep from different row
// offsets -> one wave's load burst overlaps siblings' compute. One-line
// change vs R10 for a clean A/B on the phase-lock theory.

typedef float f2 __attribute__((ext_vector_type(2)));
typedef float f4 __attribute__((ext_vector_type(4)));

constexpr float SCF = 1e-12f;
constexpr float EVF = 4.6415888336e-6f;        // 1e-32^(1/6)
constexpr float PID = 2.8559933214452666f;     // pi/1.1
constexpr float PIH = 1.5707963268f;
constexpr int   RS  = 64;                      // rows per strip
constexpr int   FT  = 40;                      // frame tasks per block

struct Row { f4 lo, hi; };                     // cols 4g..4g+3, 4g+4..4g+7

__device__ __forceinline__ float C(const Row& r, int k) {
    return k < 4 ? r.lo[k] : r.hi[k - 4];
}
__device__ __forceinline__ void load_row(Row& r, const float* p) {
    r.lo = *(const f4*)p;
    r.hi = *(const f4*)(p + 4);
}
__device__ __forceinline__ f2 mk(float a, float b) { f2 v; v.x = a; v.y = b; return v; }
__device__ __forceinline__ f2 fma2(f2 a, f2 b, f2 c) { return __builtin_elementwise_fma(a, b, c); }
__device__ __forceinline__ f2 max2(f2 a, f2 b) { return __builtin_elementwise_max(a, b); }
__device__ __forceinline__ f2 min2(f2 a, f2 b) { return __builtin_elementwise_min(a, b); }
__device__ __forceinline__ f2 abs2(f2 a) { return __builtin_elementwise_abs(a); }
__device__ __forceinline__ f2 rcp2(f2 a) {
    return mk(__builtin_amdgcn_rcpf(a.x), __builtin_amdgcn_rcpf(a.y));
}
__device__ __forceinline__ f2 rsq2(f2 a) {
    return mk(__builtin_amdgcn_rsqf(a.x), __builtin_amdgcn_rsqf(a.y));
}

// ---- packed factored math for output rows (i,i+1): R0..R5 = rows i-2..i+3
__device__ __forceinline__ f2 compute_pair(const Row& R0, const Row& R1,
                                           const Row& R2, const Row& R3,
                                           const Row& R4, const Row& R5,
                                           f2 c1, f2 c2) {
    f2 dif[6];
    #pragma unroll
    for (int k = 0; k < 6; ++k)
        dif[k] = mk(C(R3, k + 1) - C(R1, k + 1),
                    C(R4, k + 1) - C(R2, k + 1));
    f2 Pz[8];
    #pragma unroll
    for (int k = 0; k < 8; ++k)
        Pz[k] = mk(C(R2, k), C(R3, k));

    f2 part = mk(0.0f, 0.0f);
    #pragma unroll
    for (int q = 0; q < 4; ++q) {
        const f2 c00  = Pz[q + 2];
        const f2 u    = dif[q + 1];
        const f2 v    = Pz[q + 3] - Pz[q + 1];
        const f2 exxr = fma2(mk(-2.0f, -2.0f), c00,
                             mk(C(R4, q + 2) + C(R0, q + 2),
                                C(R5, q + 2) + C(R1, q + 2)));
        const f2 eyyr = fma2(mk(-2.0f, -2.0f), c00, Pz[q + 4] + Pz[q]);
        const f2 exyr = dif[q + 2] - dif[q];

        const f2 uu  = u * u;
        const f2 vv  = v * v;
        const f2 r2  = uu + vv;
        const f2 rsq = rsq2(r2);
        const f2 N   = fma2(uu, eyyr, fma2(-2.0f * (u * v), exyr, vv * exxr));
        const f2 r3  = rsq * rsq * rsq;
        const f2 kabs = abs2(N) * min2(c1 * r3, c2);
        const f2 ev   = max2(c1 * (r2 * rsq), mk(EVF, EVF));

        const f2 aw = abs2(c00 + 1e-6f);
        const f2 mx = max2(ev, aw);
        const f2 mn = min2(ev, aw);
        const f2 t  = mn * rcp2(mx);
        const f2 t2 = t * t;
        f2 pl = fma2(t2, mk(-0.01172120f, -0.01172120f), mk(0.05265332f, 0.05265332f));
        pl = fma2(t2, pl, mk(-0.11643287f, -0.11643287f));
        pl = fma2(t2, pl, mk(0.19354346f, 0.19354346f));
        pl = fma2(t2, pl, mk(-0.33262347f, -0.33262347f));
        pl = fma2(t2, pl, mk(0.99997726f, 0.99997726f));
        pl = pl * t;
        f2 at;
        at.x = (ev.x > aw.x) ? PIH - pl.x : pl.x;
        at.y = (ev.y > aw.y) ? PIH - pl.y : pl.y;

        part = part + max2(fma2(kabs, at, mk(-PID, -PID)), mk(0.0f, 0.0f));
    }
    return part;
}

// ---- scalar tail (frame) ----
__device__ __forceinline__ float penalty_scalar(float ex, float ey, float exx,
                                                float exy, float eyy, float w) {
    const float ev = fmaxf(__builtin_amdgcn_sqrtf(fmaf(ex, ex, ey * ey)), EVF);
    const float num = fmaf(ex * ex, eyy, fmaf(-2.0f * ex * ey, exy, ey * ey * exx));
    const float kabs = fabsf(num) * __builtin_amdgcn_rcpf(ev * ev * ev);
    const float aw = fabsf(w + 1e-6f);
    const float mx = fmaxf(ev, aw);
    const float mn = fminf(ev, aw);
    const float t  = mn * __builtin_amdgcn_rcpf(mx);
    const float t2 = t * t;
    float pl = fmaf(t2, -0.01172120f, 0.05265332f);
    pl = fmaf(t2, pl, -0.11643287f);
    pl = fmaf(t2, pl, 0.19354346f);
    pl = fmaf(t2, pl, -0.33262347f);
    pl = fmaf(t2, pl, 0.99997726f);
    pl *= t;
    const float at = (ev > aw) ? (PIH - pl) : pl;
    return fmaxf(fmaf(kabs, at, -PID), 0.0f);
}

// ---- global-memory edge_order=1 gradients (top/bottom rows only) ----
__device__ __forceinline__ float eg(const float* __restrict__ e, int n, int i, int j) {
    return e[(size_t)i * (size_t)n + j];
}
__device__ __forceinline__ float gex(const float* __restrict__ e, int n, int i, int j,
                                     float inv_d, float inv_2d) {
    float v;
    if (i == 0)          v = (eg(e, n, 1, j) - eg(e, n, 0, j)) * inv_d;
    else if (i == n - 1) v = (eg(e, n, n - 1, j) - eg(e, n, n - 2, j)) * inv_d;
    else                 v = (eg(e, n, i + 1, j) - eg(e, n, i - 1, j)) * inv_2d;
    return v + SCF;
}
__device__ __forceinline__ float gey(const float* __restrict__ e, int n, int i, int j,
                                     float inv_d, float inv_2d) {
    float v;
    if (j == 0)          v = (eg(e, n, i, 1) - eg(e, n, i, 0)) * inv_d;
    else if (j == n - 1) v = (eg(e, n, i, n - 1) - eg(e, n, i, n - 2)) * inv_d;
    else                 v = (eg(e, n, i, j + 1) - eg(e, n, i, j - 1)) * inv_2d;
    return v + SCF;
}

__global__ __launch_bounds__(256, 4)
void fab_fused(const float* __restrict__ eps, const float* __restrict__ gs,
               float* __restrict__ ws, int n, int G2) {
    const float d      = *gs;
    const float inv_2d = 0.5f / d;
    const float inv_d  = inv_2d + inv_2d;
    const float c1s    = inv_2d;
    const float c2s    = 1e16f * (inv_2d * inv_2d) * (inv_2d * inv_2d);
    const int bflat    = blockIdx.y * gridDim.x + blockIdx.x;

    float acc = 0.0f;

    // ================== frame: 40 tasks/block on wave 0 ====================
    if (threadIdx.x < FT) {
        const int t = bflat * FT + (int)threadIdx.x;
        const int ntop = 4 * n;
        if (t < ntop) {
            // rows {0,1,n-2,n-1} x all cols — coalesced scalar path
            const int rr = (t >= n) + (t >= 2 * n) + (t >= 3 * n);
            const int j = t - rr * n;
            const int i = (rr < 2) ? rr : (n - 4) + rr;

            const float ex0 = gex(eps, n, i, j, inv_d, inv_2d);
            const float ey0 = gey(eps, n, i, j, inv_d, inv_2d);
            float exx, exy, eyy;
            if (i == 0)
                exx = (gex(eps, n, 1, j, inv_d, inv_2d) - ex0) * inv_d;
            else if (i == n - 1)
                exx = (ex0 - gex(eps, n, n - 2, j, inv_d, inv_2d)) * inv_d;
            else
                exx = (gex(eps, n, i + 1, j, inv_d, inv_2d)
                     - gex(eps, n, i - 1, j, inv_d, inv_2d)) * inv_2d;
            if (j == 0)
                exy = (gex(eps, n, i, 1, inv_d, inv_2d) - ex0) * inv_d;
            else if (j == n - 1)
                exy = (ex0 - gex(eps, n, i, n - 2, inv_d, inv_2d)) * inv_d;
            else
                exy = (gex(eps, n, i, j + 1, inv_d, inv_2d)
                     - gex(eps, n, i, j - 1, inv_d, inv_2d)) * inv_2d;
            if (j == 0)
                eyy = (gey(eps, n, i, 1, inv_d, inv_2d) - ey0) * inv_d;
            else if (j == n - 1)
                eyy = (ey0 - gey(eps, n, i, n - 2, inv_d, inv_2d)) * inv_d;
            else
                eyy = (gey(eps, n, i, j + 1, inv_d, inv_2d)
                     - gey(eps, n, i, j - 1, inv_d, inv_2d)) * inv_2d;

            acc += penalty_scalar(ex0, ey0, exx, exy, eyy, eg(eps, n, i, j));
        } else if (t < ntop + (n - 4)) {
            // edge cols {0,1, n-6..n-1} of row i — one row per lane,
            // 15 dwordx4 into a 5x12 register window (coalesced per lane).
            const int i = 2 + (t - ntop);               // i in [2, n-3]
            float W[5][12];
            const float* rb = eps + (size_t)(i - 2) * (size_t)n;
            #pragma unroll
            for (int r = 0; r < 5; ++r) {
                const f4 a = *(const f4*)(rb + (size_t)r * n);            // cols 0..3
                const f4 b = *(const f4*)(rb + (size_t)r * n + (n - 8));  // n-8..n-5
                const f4 c = *(const f4*)(rb + (size_t)r * n + (n - 4));  // n-4..n-1
                #pragma unroll
                for (int k = 0; k < 4; ++k) {
                    W[r][k] = a[k]; W[r][4 + k] = b[k]; W[r][8 + k] = c[k];
                }
            }
            // wc: 0..3 = cols 0..3 ; 4..11 = cols n-8..n-1
            auto exW = [&](int r, int wc) {
                return (W[r + 1][wc] - W[r - 1][wc]) * inv_2d + SCF;
            };
            auto eyW = [&](int wc) {   // center row (r=2)
                if (wc == 0)  return (W[2][1] - W[2][0]) * inv_d + SCF;
                if (wc == 11) return (W[2][11] - W[2][10]) * inv_d + SCF;
                return (W[2][wc + 1] - W[2][wc - 1]) * inv_2d + SCF;
            };
            #pragma unroll
            for (int m = 0; m < 8; ++m) {
                const int wc = (m < 2) ? m : m + 4;      // {0,1,6..11}
                const float ex0 = exW(2, wc);
                const float ey0 = eyW(wc);
                const float exx = (exW(3, wc) - exW(1, wc)) * inv_2d;
                float exy, eyy;
                if (wc == 0) {
                    exy = (exW(2, 1) - exW(2, 0)) * inv_d;
                    eyy = (eyW(1) - eyW(0)) * inv_d;
                } else if (wc == 11) {
                    exy = (exW(2, 11) - exW(2, 10)) * inv_d;
                    eyy = (eyW(11) - eyW(10)) * inv_d;
                } else {
                    exy = (exW(2, wc + 1) - exW(2, wc - 1)) * inv_2d;
                    eyy = (eyW(wc + 1) - eyW(wc - 1)) * inv_2d;
                }
                acc += penalty_scalar(ex0, ey0, exx, exy, eyy, W[2][wc]);
            }
        }
    }

    // ================= inner strip, per-WAVE staggered sweep ===============
    {
        const int gg = blockIdx.x * 256 + threadIdx.x;
        const bool valid = gg < G2;
        const int gc = min(gg, G2 - 1);
        const int i0 = 2 + RS * blockIdx.y;
        const int count = min(RS, (n - 2) - i0);        // 64 or 60, even
        const float* pj = eps + 4 * (size_t)gc;         // 16B-aligned windows
        const size_t sn = (size_t)n;
        const f2 c1 = mk(c1s, c1s);
        const f2 c2 = mk(c2s, c2s);

        f2 acc2 = mk(0.0f, 0.0f);

        auto sweep = [&](int start, int len) {
            Row s0, s1, s2, s3, s4, s5, s6, s7;
            load_row(s0, pj + (size_t)(start - 2) * sn);
            load_row(s1, pj + (size_t)(start - 1) * sn);
            load_row(s2, pj + (size_t)(start    ) * sn);
            load_row(s3, pj + (size_t)(start + 1) * sn);
            load_row(s4, pj + (size_t)(start + 2) * sn);
            load_row(s5, pj + (size_t)(start + 3) * sn);
            const float* pnext = pj + (size_t)(start + 4) * sn;

            #define PHASEP(ph, A0, A1, A2, A3, A4, A5, L0, L1)                \
            {                                                                 \
                const int k = kbase + 2 * (ph);                               \
                if (k < len) {                                                \
                    if (k + 2 < len) {                                        \
                        load_row(L0, pnext);                                  \
                        load_row(L1, pnext + sn);                             \
                    }                                                         \
                    pnext += 2 * sn;                                          \
                    acc2 = acc2 + compute_pair(A0, A1, A2, A3, A4, A5,        \
                                               c1, c2);                       \
                }                                                             \
            }
            #pragma unroll 1
            for (int kbase = 0; kbase < len; kbase += 8) {
                PHASEP(0, s0, s1, s2, s3, s4, s5, s6, s7)
                PHASEP(1, s2, s3, s4, s5, s6, s7, s0, s1)
                PHASEP(2, s4, s5, s6, s7, s0, s1, s2, s3)
                PHASEP(3, s6, s7, s0, s1, s2, s3, s4, s5)
            }
            #undef PHASEP
        };

        // per-WAVE stagger: decorrelates waves within a block AND the
        // co-resident blocks {c, c+256, c+512, c+768} on one CU.
        const int wv  = (int)(threadIdx.x >> 6);
        const int off = 16 * ((wv + bflat + (bflat >> 8)) & 3);   // < count
        sweep(i0 + off, count - off);
        if (off > 0) sweep(i0, off);

        if (valid) acc += acc2.x + acc2.y;
    }

    // ---- reduction: wave -> block (LDS) -> unique ws slot ----
    __shared__ float wsum[4];
    #pragma unroll
    for (int off = 32; off; off >>= 1)
        acc += __shfl_down(acc, off, 64);
    if ((threadIdx.x & 63) == 0) wsum[threadIdx.x >> 6] = acc;
    __syncthreads();
    if (threadIdx.x == 0)
        ws[bflat] = wsum[0] + wsum[1] + wsum[2] + wsum[3];
}

__global__ __launch_bounds__(256)
void fab_finish(const float* __restrict__ ws, const float* __restrict__ gs,
                float* __restrict__ out, int nb) {
    __shared__ float wsum[4];
    float v = 0.0f;
    for (int i = threadIdx.x; i < nb; i += 256) v += ws[i];
    #pragma unroll
    for (int off = 32; off; off >>= 1)
        v += __shfl_down(v, off, 64);
    if ((threadIdx.x & 63) == 0) wsum[threadIdx.x >> 6] = v;
    __syncthreads();
    if (threadIdx.x == 0) {
        const float d = *gs;
        out[0] = (wsum[0] + wsum[1] + wsum[2] + wsum[3]) * d * d;
    }
}

extern "C" void kernel_launch(void* const* d_in, const int* in_sizes, int n_in,
                              void* d_out, int out_size, void* d_ws, size_t ws_size,
                              hipStream_t stream) {
    const float* eps = (const float*)d_in[0];
    const float* gs  = (const float*)d_in[1];
    float* out = (float*)d_out;
    float* ws  = (float*)d_ws;

    const long long tot = (long long)in_sizes[0];
    const int n = (int)(sqrt((double)tot) + 0.5);   // 8192

    const int G2 = (n - 8) / 4;                     // interior col groups
    const int nstrip = (n - 4 + RS - 1) / RS;       // 128

    dim3 block(256, 1);
    dim3 grid(n / 1024, nstrip);                    // 8 x 128 = 1024 blocks
    fab_fused<<<grid, block, 0, stream>>>(eps, gs, ws, n, G2);
    fab_finish<<<1, 256, 0, stream>>>(ws, gs, out, grid.x * grid.y);
}